// Round 1
// 826.961 us; speedup vs baseline: 1.2398x; 1.2398x over previous
//
#include <hip/hip_runtime.h>

// EideticLinearLayer via bf16 split-precision MFMA.
// out = X @ W^T + bias ; idx = searchsorted_left(quantiles[col], wx)
// X: [16384,256] f32, W: [4096,256] f32, bias: [4096], quantiles: [4096,31]
//
// fp32 -> (hi, mid) bf16 split; wx approx = hi*hi' + hi*mid' + mid*hi' via
// v_mfma_f32_16x16x32_bf16 (error ~2^-18 rel). Values within DELTA of a
// quantile boundary are recomputed with an exact sequential fp32 fmaf chain
// (same order as the reference) so indices stay bitwise-exact.

#define B_DIM 16384
#define K_DIM 256
#define N_DIM 4096
#define NQ 31
#define QCAP 2048
#define DELTA 1e-3f

typedef __bf16 bf16x8 __attribute__((ext_vector_type(8)));
typedef float f32x4 __attribute__((ext_vector_type(4)));
typedef unsigned short ushort8 __attribute__((ext_vector_type(8)));

typedef const __attribute__((address_space(1))) unsigned int gu32;
typedef __attribute__((address_space(3))) unsigned int lu32;

// ---------------------------------------------------------------------------
// split_pack: fp32 -> hi/mid bf16 planes, stored in the exact LDS tile image:
// per plane: [tiles of 128 rows][8 k-steps][4 k-octet groups][128 rows][8 k]
// so the GEMM kernel's global_load_lds staging is a pure linear 8KB copy.
// ---------------------------------------------------------------------------
__global__ __launch_bounds__(256)
void split_pack(const float* __restrict__ X, const float* __restrict__ W,
                unsigned short* __restrict__ Xhi, unsigned short* __restrict__ Xmid,
                unsigned short* __restrict__ Whi, unsigned short* __restrict__ Wmid)
{
    unsigned g = blockIdx.x * 256u + threadIdx.x;
    const float* src;
    unsigned short *dhi, *dmid;
    if (g < 524288u) {                       // X octets: 16384*256/8
        unsigned tb = g >> 12, u = g & 4095u;
        unsigned ks = u >> 9, kb = (u >> 7) & 3u, r = u & 127u;
        src = X + ((size_t)(tb * 128u + r)) * K_DIM + ks * 32u + kb * 8u;
        unsigned off = (tb * 8u + ks) * 4096u + kb * 1024u + r * 8u;
        dhi = Xhi + off; dmid = Xmid + off;
    } else {                                 // W octets: 4096*256/8
        unsigned q = g - 524288u;
        unsigned tb = q >> 12, u = q & 4095u;
        unsigned ks = u >> 9, kb = (u >> 7) & 3u, r = u & 127u;
        src = W + ((size_t)(tb * 128u + r)) * K_DIM + ks * 32u + kb * 8u;
        unsigned off = (tb * 8u + ks) * 4096u + kb * 1024u + r * 8u;
        dhi = Whi + off; dmid = Wmid + off;
    }
    float4 v0 = *(const float4*)src;
    float4 v1 = *(const float4*)(src + 4);
    float xs[8] = {v0.x, v0.y, v0.z, v0.w, v1.x, v1.y, v1.z, v1.w};
    ushort8 h8, m8;
#pragma unroll
    for (int j = 0; j < 8; ++j) {
        float x = xs[j];
        __bf16 h = (__bf16)x;            // RNE
        float hf = (float)h;
        __bf16 m = (__bf16)(x - hf);     // exact residual, then RNE
        h8[j] = __builtin_bit_cast(unsigned short, h);
        m8[j] = __builtin_bit_cast(unsigned short, m);
    }
    *(ushort8*)dhi = h8;
    *(ushort8*)dmid = m8;
}

// ---------------------------------------------------------------------------
// Main fused kernel: 128x128 tile, 4 waves (each owns a 64x64 quadrant as
// 4x4 fragments of 16x16), BK=32, double-buffered LDS, global_load_lds w=16.
// ---------------------------------------------------------------------------
__global__ __launch_bounds__(256)
void eidetic_mfma(const unsigned short* __restrict__ Xhi, const unsigned short* __restrict__ Xmid,
                  const unsigned short* __restrict__ Whi, const unsigned short* __restrict__ Wmid,
                  const float* __restrict__ X, const float* __restrict__ W,
                  const float* __restrict__ bias, const float* __restrict__ Q,
                  float* __restrict__ out, float* __restrict__ idxo)
{
    __shared__ unsigned char smem[65536];   // 2 x 32KB k-step buffers; reused for Qs+queue
    const int tid = threadIdx.x;
    const int lane = tid & 63;
    const int w = tid >> 6;
    const int wm = w >> 1, wn = w & 1;
    const int l15 = lane & 15, lg = lane >> 4;

    // XCD-aware swizzle (4096 % 8 == 0 -> bijective); nb fastest within an XCD
    const int bid = blockIdx.x;
    const int swz = ((bid & 7) << 9) | (bid >> 3);
    const int mb = swz >> 5, nb = swz & 31;
    const int m0 = mb << 7, n0 = nb << 7;

    // staging: wave 0 -> A.hi, 1 -> A.mid, 2 -> B.hi, 3 -> B.mid (8KB each)
    const unsigned short* sbase = (w == 0) ? Xhi : (w == 1) ? Xmid : (w == 2) ? Whi : Wmid;
    const int tb = (w < 2) ? mb : nb;
    const unsigned short* sp = sbase + (size_t)tb * 32768 + (size_t)lane * 8;
    const unsigned ldw = (unsigned)w * 8192u;

    // fragment addresses: plane layout [kb][row][8] -> 8 perfect bank sweeps
    const unsigned aoff = (unsigned)(lg * 128 + wm * 64 + l15) * 16u;
    const unsigned boff = 16384u + (unsigned)(lg * 128 + wn * 64 + l15) * 16u;

    f32x4 acc[4][4];
#pragma unroll
    for (int i = 0; i < 4; ++i)
#pragma unroll
        for (int j = 0; j < 4; ++j) acc[i][j] = (f32x4){0.f, 0.f, 0.f, 0.f};

    // prologue: stage k-step 0 into buffer 0
#pragma unroll
    for (int i = 0; i < 8; ++i)
        __builtin_amdgcn_global_load_lds((gu32*)(sp + i * 512),
                                         (lu32*)(smem + ldw + i * 1024), 16, 0, 0);

    for (int ks = 0; ks < 8; ++ks) {
        __syncthreads();  // compiler drains vmcnt(0): stage(ks) landed; prev reads done
        if (ks < 7) {     // stage(ks+1) flies during compute(ks)
            const unsigned short* s = sp + (ks + 1) * 4096;
            const unsigned bufn = ((unsigned)(ks + 1) & 1u) * 32768u;
#pragma unroll
            for (int i = 0; i < 8; ++i)
                __builtin_amdgcn_global_load_lds((gu32*)(s + i * 512),
                                                 (lu32*)(smem + bufn + ldw + i * 1024), 16, 0, 0);
        }
        const unsigned buf = ((unsigned)ks & 1u) * 32768u;
        bf16x8 ah[4], am[4], bh[4], bm[4];
#pragma unroll
        for (int f = 0; f < 4; ++f) {
            ah[f] = *(const bf16x8*)(smem + buf + aoff + f * 256);
            am[f] = *(const bf16x8*)(smem + buf + 8192u + aoff + f * 256);
            bh[f] = *(const bf16x8*)(smem + buf + boff + f * 256);
            bm[f] = *(const bf16x8*)(smem + buf + 8192u + boff + f * 256);
        }
#pragma unroll
        for (int fi = 0; fi < 4; ++fi)
#pragma unroll
            for (int fj = 0; fj < 4; ++fj) {
                acc[fi][fj] = __builtin_amdgcn_mfma_f32_16x16x32_bf16(ah[fi], bh[fj], acc[fi][fj], 0, 0, 0);
                acc[fi][fj] = __builtin_amdgcn_mfma_f32_16x16x32_bf16(ah[fi], bm[fj], acc[fi][fj], 0, 0, 0);
                acc[fi][fj] = __builtin_amdgcn_mfma_f32_16x16x32_bf16(am[fi], bh[fj], acc[fi][fj], 0, 0, 0);
            }
    }

    // ---- epilogue: Qs + boundary queue live in buffer 0 (last compute used buffer 1,
    // which is disjoint, so no barrier needed before these writes) ----
    float* Qs = (float*)smem;                       // 128*31*4 = 15872 B
    {
        const float* qsrc = Q + (size_t)n0 * NQ;
        for (int t = tid; t < 128 * NQ; t += 256) Qs[t] = qsrc[t];
    }
    int* qcnt = (int*)(smem + 15872);
    int* qbuf = qcnt + 1;                           // QCAP ints, ends at 24068 < 32768
    if (tid == 0) *qcnt = 0;
    __syncthreads();

    const int rb = wm * 64 + (lg << 2);             // local row base: + fi*16 + reg
#pragma unroll
    for (int fj = 0; fj < 4; ++fj) {
        const int ln = wn * 64 + fj * 16 + l15;
        const int col = n0 + ln;
        const float bv = bias[col];
        const int qb = ln * NQ;
#pragma unroll
        for (int fi = 0; fi < 4; ++fi) {
#pragma unroll
            for (int r = 0; r < 4; ++r) {
                const float v = acc[fi][fj][r];
                // branchless lower-bound (count of q < v) on 31 sorted floats
                int c = (Qs[qb + 15] < v) ? 16 : 0;
                c += (Qs[qb + c + 7] < v) ? 8 : 0;
                c += (Qs[qb + c + 3] < v) ? 4 : 0;
                c += (Qs[qb + c + 1] < v) ? 2 : 0;
                c += (Qs[qb + c] < v) ? 1 : 0;
                // boundary guard: nearest boundaries are q[c-1] (< v) and q[c] (>= v)
                bool fl = false;
                if (c > 0)  fl = (v - Qs[qb + c - 1]) < DELTA;
                if (c < NQ) fl |= (Qs[qb + c] - v) < DELTA;
                const int lrow = rb + fi * 16 + r;
                const size_t o = (size_t)(m0 + lrow) * N_DIM + col;
                out[o] = v + bv;
                idxo[o] = (float)c;
                if (fl) {
                    int slot = atomicAdd(qcnt, 1);
                    if (slot < QCAP) qbuf[slot] = (lrow << 7) | ln;
                }
            }
        }
    }

    // ---- exact recompute for boundary-ambiguous values (expected ~25/block) ----
    __syncthreads();
    int tot = *qcnt;
    if (tot > QCAP) tot = QCAP;
    for (int e = tid; e < tot; e += 256) {
        const int pk = qbuf[e];
        const int lm = pk >> 7, lc = pk & 127;
        const float* xr = X + (size_t)(m0 + lm) * K_DIM;
        const float* wr = W + (size_t)(n0 + lc) * K_DIM;
        float a = 0.f;
        // sequential fmaf chain, k ascending: bitwise-matches the reference wx
        for (int k = 0; k < K_DIM; ++k) a = fmaf(xr[k], wr[k], a);
        int c = 0;
        const int qb2 = lc * NQ;
        for (int t = 0; t < NQ; ++t) c += (Qs[qb2 + t] < a) ? 1 : 0;
        const size_t o = (size_t)(m0 + lm) * N_DIM + (n0 + lc);
        out[o] = a + bias[n0 + lc];
        idxo[o] = (float)c;
    }
}

extern "C" void kernel_launch(void* const* d_in, const int* in_sizes, int n_in,
                              void* d_out, int out_size, void* d_ws, size_t ws_size,
                              hipStream_t stream) {
    const float* x    = (const float*)d_in[0];
    const float* wgt  = (const float*)d_in[1];
    const float* bias = (const float*)d_in[2];
    const float* q    = (const float*)d_in[3];
    float* out  = (float*)d_out;
    float* idxo = out + (size_t)B_DIM * N_DIM;

    // workspace: hi/mid bf16 planes, 20.97 MB total (assumes ws_size >= 21MB)
    unsigned short* Xhi  = (unsigned short*)d_ws;
    unsigned short* Xmid = Xhi  + (size_t)B_DIM * K_DIM;
    unsigned short* Whi  = Xmid + (size_t)B_DIM * K_DIM;
    unsigned short* Wmid = Whi  + (size_t)N_DIM * K_DIM;

    hipLaunchKernelGGL(split_pack, dim3(2560), dim3(256), 0, stream,
                       x, wgt, Xhi, Xmid, Whi, Wmid);
    hipLaunchKernelGGL(eidetic_mfma, dim3(4096), dim3(256), 0, stream,
                       Xhi, Xmid, Whi, Wmid, x, wgt, bias, q, out, idxo);
}

// Round 2
// 789.294 us; speedup vs baseline: 1.2989x; 1.0477x over previous
//
#include <hip/hip_runtime.h>

// EideticLinearLayer via bf16 split-precision MFMA.
// out = X @ W^T + bias ; idx = searchsorted_left(quantiles[col], wx)
// X: [16384,256] f32, W: [4096,256] f32, bias: [4096], quantiles: [4096,31]
//
// fp32 -> (hi, mid) bf16 split; wx approx = hi*hi' + hi*mid' + mid*hi' via
// v_mfma_f32_16x16x32_bf16 (error ~2^-18 rel). Values within DELTA of a
// quantile boundary are recomputed with an exact sequential fp32 fmaf chain
// (same order as the reference) so indices stay bitwise-exact.
//
// R2 changes: (1) epilogue stores grouped per output row (fi,r outer / fj
// inner) so 128B lines are fully dirtied back-to-back -> no partial-line
// eviction RMW (was +220MB WRITE, +190MB FETCH). (2) split_pack rewritten
// with coalesced reads AND writes (thread (r,ch) owns two contiguous 16B
// chunks of the plane image), no LDS.

#define B_DIM 16384
#define K_DIM 256
#define N_DIM 4096
#define NQ 31
#define QCAP 2048
#define DELTA 1e-3f

typedef __bf16 bf16x8 __attribute__((ext_vector_type(8)));
typedef float f32x4 __attribute__((ext_vector_type(4)));
typedef unsigned short ushort8 __attribute__((ext_vector_type(8)));

typedef const __attribute__((address_space(1))) unsigned int gu32;
typedef __attribute__((address_space(3))) unsigned int lu32;

// ---------------------------------------------------------------------------
// split_pack v2: one (tile,ks) unit per block. Unit = 128 rows x 32 k of the
// source, emitted as the LDS tile image [kb(4)][row(128)][8 k] per plane.
// Thread (r = tid>>1, ch = tid&1) reads 16 consecutive floats of row r
// (64B coalesced) and writes exactly two contiguous ushort8 chunks per plane.
// ---------------------------------------------------------------------------
__global__ __launch_bounds__(256)
void split_pack(const float* __restrict__ X, const float* __restrict__ W,
                unsigned short* __restrict__ Xhi, unsigned short* __restrict__ Xmid,
                unsigned short* __restrict__ Whi, unsigned short* __restrict__ Wmid)
{
    const int b = blockIdx.x;
    const int tid = threadIdx.x;
    const int r = tid >> 1, ch = tid & 1;

    const float* src;
    unsigned short *dhi, *dmid;
    if (b < 1024) {                      // X: 128 tiles x 8 ks
        const unsigned u = b;
        src = X + ((size_t)(u >> 3) * 128 + r) * K_DIM + (u & 7) * 32 + ch * 16;
        dhi = Xhi + (size_t)u * 4096; dmid = Xmid + (size_t)u * 4096;
    } else {                             // W: 32 tiles x 8 ks
        const unsigned u = b - 1024;
        src = W + ((size_t)(u >> 3) * 128 + r) * K_DIM + (u & 7) * 32 + ch * 16;
        dhi = Whi + (size_t)u * 4096; dmid = Wmid + (size_t)u * 4096;
    }

    float4 v0 = *(const float4*)src;
    float4 v1 = *(const float4*)(src + 4);
    float4 v2 = *(const float4*)(src + 8);
    float4 v3 = *(const float4*)(src + 12);
    float xs[16] = {v0.x, v0.y, v0.z, v0.w, v1.x, v1.y, v1.z, v1.w,
                    v2.x, v2.y, v2.z, v2.w, v3.x, v3.y, v3.z, v3.w};
    ushort8 h[2], m[2];
#pragma unroll
    for (int j = 0; j < 16; ++j) {
        float x = xs[j];
        __bf16 hb = (__bf16)x;           // RNE
        float hf = (float)hb;
        __bf16 mb = (__bf16)(x - hf);    // residual, RNE
        h[j >> 3][j & 7] = __builtin_bit_cast(unsigned short, hb);
        m[j >> 3][j & 7] = __builtin_bit_cast(unsigned short, mb);
    }
    // k_local = ch*16 + j -> kb = ch*2 + (j>>3); chunk addr kb*1024 + r*8
    const unsigned off = (unsigned)(ch * 2) * 1024u + (unsigned)r * 8u;
    *(ushort8*)(dhi + off)         = h[0];
    *(ushort8*)(dhi + off + 1024)  = h[1];
    *(ushort8*)(dmid + off)        = m[0];
    *(ushort8*)(dmid + off + 1024) = m[1];
}

// ---------------------------------------------------------------------------
// Main fused kernel: 128x128 tile, 4 waves (each owns a 64x64 quadrant as
// 4x4 fragments of 16x16), BK=32, double-buffered LDS, global_load_lds w=16.
// ---------------------------------------------------------------------------
__global__ __launch_bounds__(256)
void eidetic_mfma(const unsigned short* __restrict__ Xhi, const unsigned short* __restrict__ Xmid,
                  const unsigned short* __restrict__ Whi, const unsigned short* __restrict__ Wmid,
                  const float* __restrict__ X, const float* __restrict__ W,
                  const float* __restrict__ bias, const float* __restrict__ Q,
                  float* __restrict__ out, float* __restrict__ idxo)
{
    __shared__ unsigned char smem[65536];   // 2 x 32KB k-step buffers; reused for Qs+queue
    const int tid = threadIdx.x;
    const int lane = tid & 63;
    const int w = tid >> 6;
    const int wm = w >> 1, wn = w & 1;
    const int l15 = lane & 15, lg = lane >> 4;

    // XCD-aware swizzle (4096 % 8 == 0 -> bijective); nb fastest within an XCD
    const int bid = blockIdx.x;
    const int swz = ((bid & 7) << 9) | (bid >> 3);
    const int mb = swz >> 5, nb = swz & 31;
    const int m0 = mb << 7, n0 = nb << 7;

    // staging: wave 0 -> A.hi, 1 -> A.mid, 2 -> B.hi, 3 -> B.mid (8KB each)
    const unsigned short* sbase = (w == 0) ? Xhi : (w == 1) ? Xmid : (w == 2) ? Whi : Wmid;
    const int tb = (w < 2) ? mb : nb;
    const unsigned short* sp = sbase + (size_t)tb * 32768 + (size_t)lane * 8;
    const unsigned ldw = (unsigned)w * 8192u;

    // fragment addresses: plane layout [kb][row][8] -> 8 perfect bank sweeps
    const unsigned aoff = (unsigned)(lg * 128 + wm * 64 + l15) * 16u;
    const unsigned boff = 16384u + (unsigned)(lg * 128 + wn * 64 + l15) * 16u;

    f32x4 acc[4][4];
#pragma unroll
    for (int i = 0; i < 4; ++i)
#pragma unroll
        for (int j = 0; j < 4; ++j) acc[i][j] = (f32x4){0.f, 0.f, 0.f, 0.f};

    // prologue: stage k-step 0 into buffer 0
#pragma unroll
    for (int i = 0; i < 8; ++i)
        __builtin_amdgcn_global_load_lds((gu32*)(sp + i * 512),
                                         (lu32*)(smem + ldw + i * 1024), 16, 0, 0);

    for (int ks = 0; ks < 8; ++ks) {
        __syncthreads();  // compiler drains vmcnt(0): stage(ks) landed; prev reads done
        if (ks < 7) {     // stage(ks+1) flies during compute(ks)
            const unsigned short* s = sp + (ks + 1) * 4096;
            const unsigned bufn = ((unsigned)(ks + 1) & 1u) * 32768u;
#pragma unroll
            for (int i = 0; i < 8; ++i)
                __builtin_amdgcn_global_load_lds((gu32*)(s + i * 512),
                                                 (lu32*)(smem + bufn + ldw + i * 1024), 16, 0, 0);
        }
        const unsigned buf = ((unsigned)ks & 1u) * 32768u;
        bf16x8 ah[4], am[4], bh[4], bm[4];
#pragma unroll
        for (int f = 0; f < 4; ++f) {
            ah[f] = *(const bf16x8*)(smem + buf + aoff + f * 256);
            am[f] = *(const bf16x8*)(smem + buf + 8192u + aoff + f * 256);
            bh[f] = *(const bf16x8*)(smem + buf + boff + f * 256);
            bm[f] = *(const bf16x8*)(smem + buf + 8192u + boff + f * 256);
        }
#pragma unroll
        for (int fi = 0; fi < 4; ++fi)
#pragma unroll
            for (int fj = 0; fj < 4; ++fj) {
                acc[fi][fj] = __builtin_amdgcn_mfma_f32_16x16x32_bf16(ah[fi], bh[fj], acc[fi][fj], 0, 0, 0);
                acc[fi][fj] = __builtin_amdgcn_mfma_f32_16x16x32_bf16(ah[fi], bm[fj], acc[fi][fj], 0, 0, 0);
                acc[fi][fj] = __builtin_amdgcn_mfma_f32_16x16x32_bf16(am[fi], bh[fj], acc[fi][fj], 0, 0, 0);
            }
    }

    // ---- epilogue: Qs + boundary queue live in buffer 0 (last compute used buffer 1,
    // which is disjoint, so no barrier needed before these writes) ----
    float* Qs = (float*)smem;                       // 128*31*4 = 15872 B
    {
        const float* qsrc = Q + (size_t)n0 * NQ;
        for (int t = tid; t < 128 * NQ; t += 256) Qs[t] = qsrc[t];
    }
    int* qcnt = (int*)(smem + 15872);
    int* qbuf = qcnt + 1;                           // QCAP ints, ends at 24068 < 32768
    if (tid == 0) *qcnt = 0;
    __syncthreads();

    const int rb = wm * 64 + (lg << 2);             // local row base: + fi*16 + r

    // hoisted per-fj constants
    float bv4[4]; int qb4[4]; int ln4[4];
#pragma unroll
    for (int fj = 0; fj < 4; ++fj) {
        const int ln = wn * 64 + fj * 16 + l15;
        ln4[fj] = ln;
        bv4[fj] = bias[n0 + ln];
        qb4[fj] = ln * NQ;
    }

    // fi,r outer / fj inner: each row's 4 x 64B chunks store back-to-back so
    // L2 lines fill densely (no partial-line eviction RMW).
#pragma unroll
    for (int fi = 0; fi < 4; ++fi) {
#pragma unroll
        for (int r = 0; r < 4; ++r) {
            const int lrow = rb + fi * 16 + r;
            const size_t rowo = (size_t)(m0 + lrow) * N_DIM + n0;
            float ov[4], cv[4];
#pragma unroll
            for (int fj = 0; fj < 4; ++fj) {
                const float v = acc[fi][fj][r];
                const int qb = qb4[fj];
                // branchless lower-bound (count of q < v) on 31 sorted floats
                int c = (Qs[qb + 15] < v) ? 16 : 0;
                c += (Qs[qb + c + 7] < v) ? 8 : 0;
                c += (Qs[qb + c + 3] < v) ? 4 : 0;
                c += (Qs[qb + c + 1] < v) ? 2 : 0;
                c += (Qs[qb + c] < v) ? 1 : 0;
                // boundary guard: nearest boundaries are q[c-1] (< v) and q[c] (>= v)
                bool fl = false;
                if (c > 0)  fl = (v - Qs[qb + c - 1]) < DELTA;
                if (c < NQ) fl |= (Qs[qb + c] - v) < DELTA;
                if (fl) {
                    int slot = atomicAdd(qcnt, 1);
                    if (slot < QCAP) qbuf[slot] = (lrow << 7) | ln4[fj];
                }
                ov[fj] = v + bv4[fj];
                cv[fj] = (float)c;
            }
#pragma unroll
            for (int fj = 0; fj < 4; ++fj) out[rowo + ln4[fj]]  = ov[fj];
#pragma unroll
            for (int fj = 0; fj < 4; ++fj) idxo[rowo + ln4[fj]] = cv[fj];
        }
    }

    // ---- exact recompute for boundary-ambiguous values (expected ~25/block) ----
    __syncthreads();
    int tot = *qcnt;
    if (tot > QCAP) tot = QCAP;
    for (int e = tid; e < tot; e += 256) {
        const int pk = qbuf[e];
        const int lm = pk >> 7, lc = pk & 127;
        const float* xr = X + (size_t)(m0 + lm) * K_DIM;
        const float* wr = W + (size_t)(n0 + lc) * K_DIM;
        float a = 0.f;
        // sequential fmaf chain, k ascending: bitwise-matches the reference wx
        for (int k = 0; k < K_DIM; ++k) a = fmaf(xr[k], wr[k], a);
        int c = 0;
        const int qb2 = lc * NQ;
        for (int t = 0; t < NQ; ++t) c += (Qs[qb2 + t] < a) ? 1 : 0;
        const size_t o = (size_t)(m0 + lm) * N_DIM + (n0 + lc);
        out[o] = a + bias[n0 + lc];
        idxo[o] = (float)c;
    }
}

extern "C" void kernel_launch(void* const* d_in, const int* in_sizes, int n_in,
                              void* d_out, int out_size, void* d_ws, size_t ws_size,
                              hipStream_t stream) {
    const float* x    = (const float*)d_in[0];
    const float* wgt  = (const float*)d_in[1];
    const float* bias = (const float*)d_in[2];
    const float* q    = (const float*)d_in[3];
    float* out  = (float*)d_out;
    float* idxo = out + (size_t)B_DIM * N_DIM;

    // workspace: hi/mid bf16 planes, 20.97 MB total (assumes ws_size >= 21MB)
    unsigned short* Xhi  = (unsigned short*)d_ws;
    unsigned short* Xmid = Xhi  + (size_t)B_DIM * K_DIM;
    unsigned short* Whi  = Xmid + (size_t)B_DIM * K_DIM;
    unsigned short* Wmid = Whi  + (size_t)N_DIM * K_DIM;

    hipLaunchKernelGGL(split_pack, dim3(1280), dim3(256), 0, stream,
                       x, wgt, Xhi, Xmid, Whi, Wmid);
    hipLaunchKernelGGL(eidetic_mfma, dim3(4096), dim3(256), 0, stream,
                       Xhi, Xmid, Whi, Wmid, x, wgt, bias, q, out, idxo);
}

// Round 3
// 716.036 us; speedup vs baseline: 1.4318x; 1.1023x over previous
//
#include <hip/hip_runtime.h>

// EideticLinearLayer via bf16 split-precision MFMA.
// out = X @ W^T + bias ; idx = searchsorted_left(quantiles[col], wx)
// X: [16384,256] f32, W: [4096,256] f32, bias: [4096], quantiles: [4096,31]
//
// fp32 -> (hi, mid) bf16 split; wx approx = hi*hi' + hi*mid' + mid*hi' via
// v_mfma_f32_16x16x32_bf16 (error ~2^-18 rel). Values within DELTA of a
// quantile boundary are recomputed with an exact sequential fp32 fmaf chain
// (same order as the reference) so indices stay bitwise-exact.
//
// R3 change: 512 threads / 8 waves per 128x128 block (was 256/4). Same LDS
// image (64KB, 2 blocks/CU) but 16 waves/CU instead of 8 -> occupancy
// 20%->~45% to hide stage-drain, LDS-read, search and store latency.
// Per-accumulator MFMA order unchanged -> bit-identical results.

#define B_DIM 16384
#define K_DIM 256
#define N_DIM 4096
#define NQ 31
#define QCAP 2048
#define DELTA 1e-3f

typedef __bf16 bf16x8 __attribute__((ext_vector_type(8)));
typedef float f32x4 __attribute__((ext_vector_type(4)));
typedef unsigned short ushort8 __attribute__((ext_vector_type(8)));

typedef const __attribute__((address_space(1))) unsigned int gu32;
typedef __attribute__((address_space(3))) unsigned int lu32;

// ---------------------------------------------------------------------------
// split_pack: one (tile,ks) unit per block. Unit = 128 rows x 32 k of the
// source, emitted as the LDS tile image [kb(4)][row(128)][8 k] per plane.
// Thread (r = tid>>1, ch = tid&1) reads 16 consecutive floats of row r
// (64B coalesced) and writes exactly two contiguous ushort8 chunks per plane.
// ---------------------------------------------------------------------------
__global__ __launch_bounds__(256)
void split_pack(const float* __restrict__ X, const float* __restrict__ W,
                unsigned short* __restrict__ Xhi, unsigned short* __restrict__ Xmid,
                unsigned short* __restrict__ Whi, unsigned short* __restrict__ Wmid)
{
    const int b = blockIdx.x;
    const int tid = threadIdx.x;
    const int r = tid >> 1, ch = tid & 1;

    const float* src;
    unsigned short *dhi, *dmid;
    if (b < 1024) {                      // X: 128 tiles x 8 ks
        const unsigned u = b;
        src = X + ((size_t)(u >> 3) * 128 + r) * K_DIM + (u & 7) * 32 + ch * 16;
        dhi = Xhi + (size_t)u * 4096; dmid = Xmid + (size_t)u * 4096;
    } else {                             // W: 32 tiles x 8 ks
        const unsigned u = b - 1024;
        src = W + ((size_t)(u >> 3) * 128 + r) * K_DIM + (u & 7) * 32 + ch * 16;
        dhi = Whi + (size_t)u * 4096; dmid = Wmid + (size_t)u * 4096;
    }

    float4 v0 = *(const float4*)src;
    float4 v1 = *(const float4*)(src + 4);
    float4 v2 = *(const float4*)(src + 8);
    float4 v3 = *(const float4*)(src + 12);
    float xs[16] = {v0.x, v0.y, v0.z, v0.w, v1.x, v1.y, v1.z, v1.w,
                    v2.x, v2.y, v2.z, v2.w, v3.x, v3.y, v3.z, v3.w};
    ushort8 h[2], m[2];
#pragma unroll
    for (int j = 0; j < 16; ++j) {
        float x = xs[j];
        __bf16 hb = (__bf16)x;           // RNE
        float hf = (float)hb;
        __bf16 mb = (__bf16)(x - hf);    // residual, RNE
        h[j >> 3][j & 7] = __builtin_bit_cast(unsigned short, hb);
        m[j >> 3][j & 7] = __builtin_bit_cast(unsigned short, mb);
    }
    // k_local = ch*16 + j -> kb = ch*2 + (j>>3); chunk addr kb*1024 + r*8
    const unsigned off = (unsigned)(ch * 2) * 1024u + (unsigned)r * 8u;
    *(ushort8*)(dhi + off)         = h[0];
    *(ushort8*)(dhi + off + 1024)  = h[1];
    *(ushort8*)(dmid + off)        = m[0];
    *(ushort8*)(dmid + off + 1024) = m[1];
}

// ---------------------------------------------------------------------------
// Main fused kernel: 128x128 tile, 8 waves (each owns a 64x32 quadrant as
// 4x2 fragments of 16x16), BK=32, double-buffered LDS, global_load_lds w=16.
// ---------------------------------------------------------------------------
__global__ __launch_bounds__(512, 4)
void eidetic_mfma(const unsigned short* __restrict__ Xhi, const unsigned short* __restrict__ Xmid,
                  const unsigned short* __restrict__ Whi, const unsigned short* __restrict__ Wmid,
                  const float* __restrict__ X, const float* __restrict__ W,
                  const float* __restrict__ bias, const float* __restrict__ Q,
                  float* __restrict__ out, float* __restrict__ idxo)
{
    __shared__ unsigned char smem[65536];   // 2 x 32KB k-step buffers; reused for Qs+queue
    const int tid = threadIdx.x;
    const int lane = tid & 63;
    const int w = tid >> 6;                 // 0..7
    const int wm = w >> 2, wn = w & 3;      // 2x4 wave grid over the 128x128 tile
    const int l15 = lane & 15, lg = lane >> 4;

    // XCD-aware swizzle (4096 % 8 == 0 -> bijective); nb fastest within an XCD
    const int bid = blockIdx.x;
    const int swz = ((bid & 7) << 9) | (bid >> 3);
    const int mb = swz >> 5, nb = swz & 31;
    const int m0 = mb << 7, n0 = nb << 7;

    // staging: plane p = w>>1 (0 A.hi, 1 A.mid, 2 B.hi, 3 B.mid), half h = w&1
    const int p = w >> 1, h = w & 1;
    const unsigned short* sbase = (p == 0) ? Xhi : (p == 1) ? Xmid : (p == 2) ? Whi : Wmid;
    const int tb = (p < 2) ? mb : nb;
    const unsigned short* sp = sbase + (size_t)tb * 32768 + h * 2048 + (size_t)lane * 8;
    const unsigned ldw = (unsigned)p * 8192u + (unsigned)h * 4096u;

    // fragment addresses: plane layout [kb][row][8] -> contiguous 256B per 16-lane group
    const unsigned abase = (unsigned)(lg * 128 + wm * 64 + l15) * 16u;
    const unsigned bbase = 16384u + (unsigned)(lg * 128 + wn * 32 + l15) * 16u;

    f32x4 acc[4][2];
#pragma unroll
    for (int i = 0; i < 4; ++i)
#pragma unroll
        for (int j = 0; j < 2; ++j) acc[i][j] = (f32x4){0.f, 0.f, 0.f, 0.f};

    // prologue: stage k-step 0 into buffer 0 (each wave: 4x16B per lane = its half-plane)
#pragma unroll
    for (int i = 0; i < 4; ++i)
        __builtin_amdgcn_global_load_lds((gu32*)(sp + i * 512),
                                         (lu32*)(smem + ldw + i * 1024), 16, 0, 0);

    for (int ks = 0; ks < 8; ++ks) {
        __syncthreads();  // compiler drains vmcnt(0): stage(ks) landed; prev reads done
        if (ks < 7) {     // stage(ks+1) flies during compute(ks)
            const unsigned short* s = sp + (ks + 1) * 4096;
            const unsigned bufn = ((unsigned)(ks + 1) & 1u) * 32768u;
#pragma unroll
            for (int i = 0; i < 4; ++i)
                __builtin_amdgcn_global_load_lds((gu32*)(s + i * 512),
                                                 (lu32*)(smem + bufn + ldw + i * 1024), 16, 0, 0);
        }
        const unsigned buf = ((unsigned)ks & 1u) * 32768u;
        bf16x8 ah[4], am[4], bh[2], bm[2];
#pragma unroll
        for (int f = 0; f < 4; ++f) {
            ah[f] = *(const bf16x8*)(smem + buf + abase + f * 256);
            am[f] = *(const bf16x8*)(smem + buf + 8192u + abase + f * 256);
        }
#pragma unroll
        for (int f = 0; f < 2; ++f) {
            bh[f] = *(const bf16x8*)(smem + buf + bbase + f * 256);
            bm[f] = *(const bf16x8*)(smem + buf + 8192u + bbase + f * 256);
        }
#pragma unroll
        for (int fi = 0; fi < 4; ++fi)
#pragma unroll
            for (int fj = 0; fj < 2; ++fj) {
                acc[fi][fj] = __builtin_amdgcn_mfma_f32_16x16x32_bf16(ah[fi], bh[fj], acc[fi][fj], 0, 0, 0);
                acc[fi][fj] = __builtin_amdgcn_mfma_f32_16x16x32_bf16(ah[fi], bm[fj], acc[fi][fj], 0, 0, 0);
                acc[fi][fj] = __builtin_amdgcn_mfma_f32_16x16x32_bf16(am[fi], bh[fj], acc[fi][fj], 0, 0, 0);
            }
    }

    // ---- epilogue: Qs + boundary queue live in buffer 0 (last compute used buffer 1,
    // which is disjoint, so no barrier needed before these writes) ----
    float* Qs = (float*)smem;                       // 128*31*4 = 15872 B
    {
        const float* qsrc = Q + (size_t)n0 * NQ;
        for (int t = tid; t < 128 * NQ; t += 512) Qs[t] = qsrc[t];
    }
    int* qcnt = (int*)(smem + 15872);
    int* qbuf = qcnt + 1;                           // QCAP ints, ends at 24068 < 32768
    if (tid == 0) *qcnt = 0;
    __syncthreads();

    const int rb = wm * 64 + (lg << 2);             // local row base: + fi*16 + r

    // hoisted per-fj constants
    float bv2[2]; int qb2[2]; int ln2[2];
#pragma unroll
    for (int fj = 0; fj < 2; ++fj) {
        const int ln = wn * 32 + fj * 16 + l15;
        ln2[fj] = ln;
        bv2[fj] = bias[n0 + ln];
        qb2[fj] = ln * NQ;
    }

    // fi,r outer / fj inner: each row's chunks store back-to-back so L2 lines
    // fill densely (no partial-line eviction RMW).
#pragma unroll
    for (int fi = 0; fi < 4; ++fi) {
#pragma unroll
        for (int r = 0; r < 4; ++r) {
            const int lrow = rb + fi * 16 + r;
            const size_t rowo = (size_t)(m0 + lrow) * N_DIM + n0;
            float ov[2], cv[2];
#pragma unroll
            for (int fj = 0; fj < 2; ++fj) {
                const float v = acc[fi][fj][r];
                const int qb = qb2[fj];
                // branchless lower-bound (count of q < v) on 31 sorted floats
                int c = (Qs[qb + 15] < v) ? 16 : 0;
                c += (Qs[qb + c + 7] < v) ? 8 : 0;
                c += (Qs[qb + c + 3] < v) ? 4 : 0;
                c += (Qs[qb + c + 1] < v) ? 2 : 0;
                c += (Qs[qb + c] < v) ? 1 : 0;
                // boundary guard: nearest boundaries are q[c-1] (< v) and q[c] (>= v)
                bool fl = false;
                if (c > 0)  fl = (v - Qs[qb + c - 1]) < DELTA;
                if (c < NQ) fl |= (Qs[qb + c] - v) < DELTA;
                if (fl) {
                    int slot = atomicAdd(qcnt, 1);
                    if (slot < QCAP) qbuf[slot] = (lrow << 7) | ln2[fj];
                }
                ov[fj] = v + bv2[fj];
                cv[fj] = (float)c;
            }
#pragma unroll
            for (int fj = 0; fj < 2; ++fj) out[rowo + ln2[fj]]  = ov[fj];
#pragma unroll
            for (int fj = 0; fj < 2; ++fj) idxo[rowo + ln2[fj]] = cv[fj];
        }
    }

    // ---- exact recompute for boundary-ambiguous values (expected ~25/block) ----
    __syncthreads();
    int tot = *qcnt;
    if (tot > QCAP) tot = QCAP;
    for (int e = tid; e < tot; e += 512) {
        const int pk = qbuf[e];
        const int lm = pk >> 7, lc = pk & 127;
        const float* xr = X + (size_t)(m0 + lm) * K_DIM;
        const float* wr = W + (size_t)(n0 + lc) * K_DIM;
        float a = 0.f;
        // sequential fmaf chain, k ascending: bitwise-matches the reference wx
        for (int k = 0; k < K_DIM; ++k) a = fmaf(xr[k], wr[k], a);
        int c = 0;
        const int qb2s = lc * NQ;
        for (int t = 0; t < NQ; ++t) c += (Qs[qb2s + t] < a) ? 1 : 0;
        const size_t o = (size_t)(m0 + lm) * N_DIM + (n0 + lc);
        out[o] = a + bias[n0 + lc];
        idxo[o] = (float)c;
    }
}

extern "C" void kernel_launch(void* const* d_in, const int* in_sizes, int n_in,
                              void* d_out, int out_size, void* d_ws, size_t ws_size,
                              hipStream_t stream) {
    const float* x    = (const float*)d_in[0];
    const float* wgt  = (const float*)d_in[1];
    const float* bias = (const float*)d_in[2];
    const float* q    = (const float*)d_in[3];
    float* out  = (float*)d_out;
    float* idxo = out + (size_t)B_DIM * N_DIM;

    // workspace: hi/mid bf16 planes, 20.97 MB total (assumes ws_size >= 21MB)
    unsigned short* Xhi  = (unsigned short*)d_ws;
    unsigned short* Xmid = Xhi  + (size_t)B_DIM * K_DIM;
    unsigned short* Whi  = Xmid + (size_t)B_DIM * K_DIM;
    unsigned short* Wmid = Whi  + (size_t)N_DIM * K_DIM;

    hipLaunchKernelGGL(split_pack, dim3(1280), dim3(256), 0, stream,
                       x, wgt, Xhi, Xmid, Whi, Wmid);
    hipLaunchKernelGGL(eidetic_mfma, dim3(4096), dim3(512), 0, stream,
                       Xhi, Xmid, Whi, Wmid, x, wgt, bias, q, out, idxo);
}